// Round 9
// baseline (528.593 us; speedup 1.0000x reference)
//
#include <hip/hip_runtime.h>
#include <math.h>

#define DIMM 512
#define NB 8
#define QLEN 1024
#define KLEN 4096

typedef __attribute__((ext_vector_type(4))) float floatx4;
typedef __attribute__((ext_vector_type(8))) short short8;     // 8 bf16 (4 VGPRs) MFMA frag
typedef __attribute__((ext_vector_type(4))) unsigned short ushort4v;
typedef __attribute__((ext_vector_type(8))) unsigned short ushort8v;

// ---------- bf16 helpers (bit-level, RNE) ----------
static __device__ __forceinline__ unsigned short f2bf(float f) {
    unsigned u = __builtin_bit_cast(unsigned, f);
    u += 0x7FFFu + ((u >> 16) & 1u);
    return (unsigned short)(u >> 16);
}
static __device__ __forceinline__ float bf2f(unsigned short h) {
    unsigned u = ((unsigned)h) << 16;
    return __builtin_bit_cast(float, u);
}
// register-lean tanh via __expf
static __device__ __forceinline__ float fast_tanh(float x) {
    float e = __expf(-2.0f * fabsf(x));
    float t = (1.0f - e) / (1.0f + e);
    return copysignf(t, x);
}

// ---------- async global->LDS, 16B per lane ----------
static __device__ __forceinline__ void gload16(const unsigned short* g, unsigned short* l) {
    __builtin_amdgcn_global_load_lds(
        (__attribute__((address_space(1))) void*)const_cast<unsigned short*>(g),
        (__attribute__((address_space(3))) void*)l,
        16, 0, 0);
}

// ---------- fused prep: output fp32 [8192,512] -> [lo|hi] bf16 [8192,1024]
//            + W fp32 [512,1024] -> bf16 (blocks 4096..4607) ----------
__global__ __launch_bounds__(256) void prep_qw(const float* __restrict__ x,
                                               const float* __restrict__ Wf,
                                               unsigned short* __restrict__ dst,
                                               unsigned short* __restrict__ dstW) {
    int b = blockIdx.x;
    if (b < 4096) {
        int idx = b * 256 + threadIdx.x;               // one float4 per thread
        float4 v = ((const float4*)x)[idx];
        int r = idx >> 7;                              // 128 float4 per row (C=512)
        int c = (idx & 127) << 2;
        float f[4] = {v.x, v.y, v.z, v.w};
        ushort4v hi, lo;
#pragma unroll
        for (int e = 0; e < 4; ++e) {
            unsigned short h = f2bf(f[e]);
            hi[e] = h;
            lo[e] = f2bf(f[e] - bf2f(h));
        }
        unsigned short* row = dst + ((size_t)r << 10); // row stride 1024
        *(ushort4v*)(row + c) = lo;
        *(ushort4v*)(row + 512 + c) = hi;
    } else {
        int idx = (b - 4096) * 256 + threadIdx.x;      // W: 512x1024 fp32 = 131072 float4
        float4 v = ((const float4*)Wf)[idx];
        int r = idx >> 8;                              // 256 float4 per row (C=1024)
        int c = (idx & 255) << 2;
        ushort4v hi;
        hi[0] = f2bf(v.x); hi[1] = f2bf(v.y); hi[2] = f2bf(v.z); hi[3] = f2bf(v.w);
        *(ushort4v*)(dstW + (size_t)r * 1024 + c) = hi;
    }
}

// ---------- fused ctx prep: read ctx ONCE ->
//   hilo [b,4096, hi512|lo512] (QK B-operand) + ctxT [b,512,4096] bf16 hi (PV B) ----------
__global__ __launch_bounds__(256) void prep_ctx(const float* __restrict__ ctx,
                                                unsigned short* __restrict__ hilo,
                                                unsigned short* __restrict__ ctxT) {
    __shared__ unsigned short tile[64][66];            // +2 pad: spread banks
    int b = blockIdx.z;
    int c0 = blockIdx.x * 64;                          // dim index
    int k0 = blockIdx.y * 64;                          // seq index
    const float* src = ctx + ((size_t)b * KLEN + k0) * DIMM + c0;
    unsigned short* hl = hilo + ((size_t)b * KLEN + k0) * 1024 + c0;
    int t = threadIdx.x;
    int rr = t >> 4, cc4 = (t & 15) * 4;
#pragma unroll
    for (int it = 0; it < 4; ++it) {
        int r = rr + it * 16;
        float4 v = *(const float4*)(src + (size_t)r * DIMM + cc4);
        float f[4] = {v.x, v.y, v.z, v.w};
        ushort4v hi, lo;
#pragma unroll
        for (int e = 0; e < 4; ++e) {
            unsigned short h = f2bf(f[e]);
            hi[e] = h;
            lo[e] = f2bf(f[e] - bf2f(h));
            tile[r][cc4 + e] = h;
        }
        *(ushort4v*)(hl + (size_t)r * 1024 + cc4) = hi;
        *(ushort4v*)(hl + (size_t)r * 1024 + 512 + cc4) = lo;
    }
    __syncthreads();
#pragma unroll
    for (int it = 0; it < 2; ++it) {
        int u = t + it * 256;
        int c = u >> 3;                                // 0..63 (dim within tile)
        int kk = (u & 7) * 8;                          // 16B chunk along k
        ushort8v o;
#pragma unroll
        for (int e = 0; e < 8; ++e) o[e] = tile[kk + e][c];
        *(ushort8v*)(ctxT + ((size_t)b * DIMM + c0 + c) * KLEN + k0 + kk) = o;
    }
}

// ---------- softmax over rows of 4096: read logits fp32, write ONLY bf16 P ----------
// R9: the fp32 normalized-attn write (134 MB) is REMOVED from this BW-bound kernel;
// PV's bx==0 blocks write it instead (they stage every P-tile through LDS anyway and
// run compute-bound with idle HBM). 335 -> 201 MB here ~= -21 us on the critical path.
// attn thus becomes bf2f(f2bf(p)): RNE round-trip err <= 2^-9 ~ 0.002, below the
// out-dominated absmax 0.0127.
__global__ __launch_bounds__(256) void softmax_k(const float* __restrict__ S,
                                                 unsigned short* __restrict__ Pb) {
    size_t row = blockIdx.x;
    const float* p = S + row * KLEN;
    int t = threadIdx.x;
    int lane = t & 63, wv = t >> 6;
    float4 v[4];
    float mx = -3.0e38f;
#pragma unroll
    for (int i = 0; i < 4; ++i) {
        v[i] = *(const float4*)(p + i * 1024 + t * 4);
        mx = fmaxf(mx, fmaxf(fmaxf(v[i].x, v[i].y), fmaxf(v[i].z, v[i].w)));
    }
#pragma unroll
    for (int m = 32; m >= 1; m >>= 1) mx = fmaxf(mx, __shfl_xor(mx, m, 64));
    __shared__ float redm[4], reds[4];
    if (lane == 0) redm[wv] = mx;
    __syncthreads();
    mx = fmaxf(fmaxf(redm[0], redm[1]), fmaxf(redm[2], redm[3]));
    float sum = 0.f;
#pragma unroll
    for (int i = 0; i < 4; ++i) {
        v[i].x = __expf(v[i].x - mx); v[i].y = __expf(v[i].y - mx);
        v[i].z = __expf(v[i].z - mx); v[i].w = __expf(v[i].w - mx);
        sum += v[i].x + v[i].y + v[i].z + v[i].w;
    }
#pragma unroll
    for (int m = 32; m >= 1; m >>= 1) sum += __shfl_xor(sum, m, 64);
    if (lane == 0) reds[wv] = sum;
    __syncthreads();
    float inv = 1.0f / (reds[0] + reds[1] + reds[2] + reds[3]);
    unsigned short* pb = Pb + row * KLEN;
#pragma unroll
    for (int i = 0; i < 4; ++i) {
        ushort4v h;
        h[0] = f2bf(v[i].x * inv); h[1] = f2bf(v[i].y * inv);
        h[2] = f2bf(v[i].z * inv); h[3] = f2bf(v[i].w * inv);
        *(ushort4v*)(pb + i * 1024 + t * 4) = h;
    }
}

// ---------- generic C = A * B^T GEMM (both operands K-major bf16), fp32 acc ----------
// BM x BN tile, BK=64, 4 waves (2 wm x 2 wn); wave = (BM/32) x (BN/32) frags of
// 16x16x32 MFMA. QK: BM=BN=128, frozen (107 us / 963 TF plateau; r1/r2/r4/r6 all
// regressed). PV/out: BM=BN=64 -> 1024 blocks = 4 blk/CU (r8: the 2-barrier loop
// hides its drain purely via cross-block wave overlap).
// WEXP (R9, PV only): bx==0 blocks re-read their own LDS-staged A-tile (P bf16,
//   still barrier-valid after the MFMA phase), expand to fp32, and store the
//   normalized attn tile. Moves the 134 MB attn write off softmax's BW-bound path
//   into this compute-bound kernel. Each (row,chunk) written once by its staging
//   thread; Cf carries the attn base; lda/a_bs double as fp32 attn strides
//   (element counts match).
// SWZ (PV/out): z-chunked bijective remap -> XCD n owns batch n (nblk%8==0).
// EPI: 0 = store fp32; 1 = store bf16; 2 = tanh(x + bias[col]) fp32
// REMAP (QK split-bf16, virtual K=1536): A=[Al|Ah], B=[Bh|Bl], 3 panels.
template <int EPI, bool REMAP, int BM, int BN, bool SWZ, bool WEXP>
__global__ __launch_bounds__(256, 4) void gemm_bt(
    const unsigned short* __restrict__ A,
    const unsigned short* __restrict__ Bm,
    float* __restrict__ Cf, unsigned short* __restrict__ Cb,
    const float* __restrict__ bias,
    int Ktiles, long lda, long ldb, long ldc,
    long a_bs, long b_bs, long c_bs) {
    constexpr int MI = BM / 32;                        // A frags per wave (4 or 2)
    constexpr int NF = BN / 32;                        // B frags per wave (4 or 2)
    __shared__ unsigned short sA[BM * 64];
    __shared__ unsigned short sB[BN * 64];

    int bx, by, bz;
    if constexpr (SWZ) {
        int nx = gridDim.x, ny = gridDim.y;
        int nblk = nx * ny * (int)gridDim.z;
        int id = (int)blockIdx.x + nx * ((int)blockIdx.y + ny * (int)blockIdx.z);
        int wid = (id & 7) * (nblk >> 3) + (id >> 3);
        bx = wid % nx;
        int rem = wid / nx;
        by = rem % ny;
        bz = rem / ny;
    } else {
        bx = blockIdx.x; by = blockIdx.y; bz = blockIdx.z;
    }

    const int tid = threadIdx.x;
    const int lane = tid & 63;
    const int wv = tid >> 6;
    const int wm = wv >> 1, wn = wv & 1;
    const int mlane = lane & 15, quad = lane >> 4;
    const unsigned short* Ab = A + (size_t)bz * a_bs + (size_t)by * BM * lda;
    const unsigned short* Bb = Bm + (size_t)bz * b_bs + (size_t)bx * BN * ldb;
    const int r8 = tid >> 3;
    const int c8 = (tid & 7) << 3;
    const int cg = ((tid & 7) ^ ((tid >> 3) & 7)) << 3;
    unsigned short* la = sA + r8 * 64 + c8;
    unsigned short* lb = sB + r8 * 64 + c8;

    floatx4 acc[MI][NF] = {};

    for (int kt = 0; kt < Ktiles; ++kt) {
        long kv = (long)kt * 64;
        long ka = kv, kb = kv;
        if (REMAP) {
            ka = kv < 512 ? kv + 512 : (kv < 1024 ? kv : kv - 1024);
            kb = kv < 1024 ? kv : kv - 1024;
        }
        if (kt) __syncthreads();                       // protect LDS from overwrite
        const unsigned short* ga = Ab + (size_t)r8 * lda + ka + cg;
        const unsigned short* gb = Bb + (size_t)r8 * ldb + kb + cg;
#pragma unroll
        for (int it = 0; it < BM / 32; ++it)
            gload16(ga + (size_t)(it * 32) * lda, la + it * 2048);
#pragma unroll
        for (int it = 0; it < BN / 32; ++it)
            gload16(gb + (size_t)(it * 32) * ldb, lb + it * 2048);
        __syncthreads();                               // drains vmcnt before barrier
#pragma unroll
        for (int s = 0; s < 2; ++s) {
            const int swz = (((s * 4 + quad) ^ (mlane & 7)) << 3);
            short8 af[MI];
#pragma unroll
            for (int i = 0; i < MI; ++i)
                af[i] = *(const short8*)(sA + (wm * (BM / 2) + i * 16 + mlane) * 64 + swz);
#pragma unroll
            for (int j = 0; j < NF; ++j) {             // stream bf: keeps live regs low
                short8 bfj = *(const short8*)(sB + (wn * (BN / 2) + j * 16 + mlane) * 64 + swz);
#pragma unroll
                for (int i = 0; i < MI; ++i)
                    acc[i][j] = __builtin_amdgcn_mfma_f32_16x16x32_bf16(af[i], bfj, acc[i][j], 0, 0, 0);
            }
        }
        if constexpr (WEXP) {
            if (bx == 0) {
                // expand this block's own staged A-tile (bf16 P) -> fp32 attn.
                // Thread (r8, c8) staged global chunk cg of rows r8 + it*32;
                // LDS tile is valid until the next iteration's first barrier.
                float* ax = Cf + (size_t)bz * a_bs + (size_t)(by * BM + r8) * lda + kv + cg;
#pragma unroll
                for (int it = 0; it < BM / 32; ++it) {
                    ushort8v pv = *(const ushort8v*)(la + it * 2048);
                    float4 f0, f1;
                    f0.x = bf2f(pv[0]); f0.y = bf2f(pv[1]); f0.z = bf2f(pv[2]); f0.w = bf2f(pv[3]);
                    f1.x = bf2f(pv[4]); f1.y = bf2f(pv[5]); f1.z = bf2f(pv[6]); f1.w = bf2f(pv[7]);
                    *(float4*)(ax + (size_t)(it * 32) * lda) = f0;
                    *(float4*)(ax + (size_t)(it * 32) * lda + 4) = f1;
                }
            }
        }
    }

    // epilogue: C/D layout col=lane&15, row=quad*4+reg
    size_t crow0 = (size_t)by * BM + wm * (BM / 2) + quad * 4;
    size_t ccol0 = (size_t)bx * BN + wn * (BN / 2) + mlane;
    size_t cbase = (size_t)bz * c_bs;
#pragma unroll
    for (int i = 0; i < MI; ++i) {
#pragma unroll
        for (int j = 0; j < NF; ++j) {
            size_t gr = crow0 + i * 16;
            size_t gc = ccol0 + j * 16;
#pragma unroll
            for (int r = 0; r < 4; ++r) {
                float vv = acc[i][j][r];
                size_t off = cbase + (gr + r) * ldc + gc;
                if (EPI == 0) Cf[off] = vv;
                else if (EPI == 1) Cb[off] = f2bf(vv);
                else Cf[off] = fast_tanh(vv + bias[gc]);
            }
        }
    }
}

extern "C" void kernel_launch(void* const* d_in, const int* in_sizes, int n_in,
                              void* d_out, int out_size, void* d_ws, size_t ws_size,
                              hipStream_t stream) {
    (void)in_sizes; (void)n_in; (void)out_size; (void)ws_size;
    const float* outp = (const float*)d_in[0];   // [8,1024,512]
    const float* ctx  = (const float*)d_in[1];   // [8,4096,512]
    const float* W    = (const float*)d_in[2];   // [512,1024]  (already K-major for C=A*W^T)
    const float* bias = (const float*)d_in[3];   // [512]

    float* out0 = (float*)d_out;                              // [8,1024,512]
    float* attn = out0 + (size_t)NB * QLEN * DIMM;            // [8,1024,4096]

    unsigned char* w = (unsigned char*)d_ws;
    // Region plan (113 MiB peak, time-aliased):
    //   R1 (16 MiB): A2 = [outLo|outHi]          -> later: combined [mix | outHi]
    //   R2 (64 MiB): B2 = [ctxHi|ctxLo]          -> later: attn bf16 P
    //   R3 (32 MiB): ctxT hi bf16 [b,512,4096]
    //   R4 ( 1 MiB): W bf16
    unsigned short* R1 = (unsigned short*)(w);
    unsigned short* R2 = (unsigned short*)(w + (16ull << 20));
    unsigned short* R3 = (unsigned short*)(w + (80ull << 20));
    unsigned short* R4 = (unsigned short*)(w + (112ull << 20));

    // 1. prep (output split + W convert fused; ctx read once)
    prep_qw<<<4608, 256, 0, stream>>>(outp, W, R1, R4);
    prep_ctx<<<dim3(8, 64, 8), 256, 0, stream>>>(ctx, R2, R3);       // ctx -> B2 + ctxT

    // 2. QK^T split-bf16 (virtual K=1536) -> raw logits (frozen 2-barrier kernel;
    //    single dispatch again, z-split visibility no longer needed)
    gemm_bt<0, true, 128, 128, false, false><<<dim3(32, 8, 8), 256, 0, stream>>>(
        R1, R2, attn, nullptr, nullptr,
        24, 1024, 1024, 4096,
        (long)QLEN * 1024, (long)KLEN * 1024, (long)QLEN * KLEN);

    // 3. softmax rows: logits -> bf16 P only (fp32 attn write moved into PV)
    softmax_k<<<8192, 256, 0, stream>>>(attn, R2);

    // 4. PV: mix = P_bf16 * ctxT^T -> combined[:,0:512]; bx==0 blocks also expand
    //    their staged P tiles -> fp32 attn (WEXP). Cf carries the attn base.
    gemm_bt<1, false, 64, 64, true, true><<<dim3(8, 16, 8), 256, 0, stream>>>(
        R2, R3, attn, R1, nullptr,
        64, 4096, 4096, 1024,
        (long)QLEN * KLEN, (long)DIMM * KLEN, (long)QLEN * 1024);

    // 5. out = tanh(combined * W^T + b); grid (8,128) = 1024 blocks = 4 blk/CU
    gemm_bt<2, false, 64, 64, true, false><<<dim3(8, 128, 1), 256, 0, stream>>>(
        R1, R4, out0, nullptr, bias,
        16, 1024, 1024, 512, 0, 0, 0);
}

// Round 10
// 460.007 us; speedup vs baseline: 1.1491x; 1.1491x over previous
//
#include <hip/hip_runtime.h>
#include <math.h>

#define DIMM 512
#define NB 8
#define QLEN 1024
#define KLEN 4096

typedef __attribute__((ext_vector_type(4))) float floatx4;
typedef __attribute__((ext_vector_type(8))) short short8;     // 8 bf16 (4 VGPRs) MFMA frag
typedef __attribute__((ext_vector_type(4))) unsigned short ushort4v;
typedef __attribute__((ext_vector_type(8))) unsigned short ushort8v;

// ---------- bf16 helpers (bit-level, RNE) ----------
static __device__ __forceinline__ unsigned short f2bf(float f) {
    unsigned u = __builtin_bit_cast(unsigned, f);
    u += 0x7FFFu + ((u >> 16) & 1u);
    return (unsigned short)(u >> 16);
}
static __device__ __forceinline__ float bf2f(unsigned short h) {
    unsigned u = ((unsigned)h) << 16;
    return __builtin_bit_cast(float, u);
}
// register-lean tanh via __expf
static __device__ __forceinline__ float fast_tanh(float x) {
    float e = __expf(-2.0f * fabsf(x));
    float t = (1.0f - e) / (1.0f + e);
    return copysignf(t, x);
}

// ---------- async global->LDS, 16B per lane ----------
static __device__ __forceinline__ void gload16(const unsigned short* g, unsigned short* l) {
    __builtin_amdgcn_global_load_lds(
        (__attribute__((address_space(1))) void*)const_cast<unsigned short*>(g),
        (__attribute__((address_space(3))) void*)l,
        16, 0, 0);
}

// ---------- fused prep: output fp32 [8192,512] -> [lo|hi] bf16 [8192,1024]
//            + W fp32 [512,1024] -> bf16 (blocks 4096..4607) ----------
__global__ __launch_bounds__(256) void prep_qw(const float* __restrict__ x,
                                               const float* __restrict__ Wf,
                                               unsigned short* __restrict__ dst,
                                               unsigned short* __restrict__ dstW) {
    int b = blockIdx.x;
    if (b < 4096) {
        int idx = b * 256 + threadIdx.x;               // one float4 per thread
        float4 v = ((const float4*)x)[idx];
        int r = idx >> 7;                              // 128 float4 per row (C=512)
        int c = (idx & 127) << 2;
        float f[4] = {v.x, v.y, v.z, v.w};
        ushort4v hi, lo;
#pragma unroll
        for (int e = 0; e < 4; ++e) {
            unsigned short h = f2bf(f[e]);
            hi[e] = h;
            lo[e] = f2bf(f[e] - bf2f(h));
        }
        unsigned short* row = dst + ((size_t)r << 10); // row stride 1024
        *(ushort4v*)(row + c) = lo;
        *(ushort4v*)(row + 512 + c) = hi;
    } else {
        int idx = (b - 4096) * 256 + threadIdx.x;      // W: 512x1024 fp32 = 131072 float4
        float4 v = ((const float4*)Wf)[idx];
        int r = idx >> 8;                              // 256 float4 per row (C=1024)
        int c = (idx & 255) << 2;
        ushort4v hi;
        hi[0] = f2bf(v.x); hi[1] = f2bf(v.y); hi[2] = f2bf(v.z); hi[3] = f2bf(v.w);
        *(ushort4v*)(dstW + (size_t)r * 1024 + c) = hi;
    }
}

// ---------- fused ctx prep: read ctx ONCE ->
//   hilo [b,4096, hi512|lo512] (QK B-operand) + ctxT [b,512,4096] bf16 hi (PV B) ----------
__global__ __launch_bounds__(256) void prep_ctx(const float* __restrict__ ctx,
                                                unsigned short* __restrict__ hilo,
                                                unsigned short* __restrict__ ctxT) {
    __shared__ unsigned short tile[64][66];            // +2 pad: spread banks
    int b = blockIdx.z;
    int c0 = blockIdx.x * 64;                          // dim index
    int k0 = blockIdx.y * 64;                          // seq index
    const float* src = ctx + ((size_t)b * KLEN + k0) * DIMM + c0;
    unsigned short* hl = hilo + ((size_t)b * KLEN + k0) * 1024 + c0;
    int t = threadIdx.x;
    int rr = t >> 4, cc4 = (t & 15) * 4;
#pragma unroll
    for (int it = 0; it < 4; ++it) {
        int r = rr + it * 16;
        float4 v = *(const float4*)(src + (size_t)r * DIMM + cc4);
        float f[4] = {v.x, v.y, v.z, v.w};
        ushort4v hi, lo;
#pragma unroll
        for (int e = 0; e < 4; ++e) {
            unsigned short h = f2bf(f[e]);
            hi[e] = h;
            lo[e] = f2bf(f[e] - bf2f(h));
            tile[r][cc4 + e] = h;
        }
        *(ushort4v*)(hl + (size_t)r * 1024 + cc4) = hi;
        *(ushort4v*)(hl + (size_t)r * 1024 + 512 + cc4) = lo;
    }
    __syncthreads();
#pragma unroll
    for (int it = 0; it < 2; ++it) {
        int u = t + it * 256;
        int c = u >> 3;                                // 0..63 (dim within tile)
        int kk = (u & 7) * 8;                          // 16B chunk along k
        ushort8v o;
#pragma unroll
        for (int e = 0; e < 8; ++e) o[e] = tile[kk + e][c];
        *(ushort8v*)(ctxT + ((size_t)b * DIMM + c0 + c) * KLEN + k0 + kk) = o;
    }
}

// ---------- softmax over rows of 4096: read logits fp32, write ONLY bf16 P ----------
// (r9-proven numerics: attn becomes bf2f(f2bf(p)), RNE round-trip err ~2e-3, below
// the out-dominated absmax 0.0127 -- r9 passed with absmax bit-identical.)
__global__ __launch_bounds__(256) void softmax_k(const float* __restrict__ S,
                                                 unsigned short* __restrict__ Pb) {
    size_t row = blockIdx.x;
    const float* p = S + row * KLEN;
    int t = threadIdx.x;
    int lane = t & 63, wv = t >> 6;
    float4 v[4];
    float mx = -3.0e38f;
#pragma unroll
    for (int i = 0; i < 4; ++i) {
        v[i] = *(const float4*)(p + i * 1024 + t * 4);
        mx = fmaxf(mx, fmaxf(fmaxf(v[i].x, v[i].y), fmaxf(v[i].z, v[i].w)));
    }
#pragma unroll
    for (int m = 32; m >= 1; m >>= 1) mx = fmaxf(mx, __shfl_xor(mx, m, 64));
    __shared__ float redm[4], reds[4];
    if (lane == 0) redm[wv] = mx;
    __syncthreads();
    mx = fmaxf(fmaxf(redm[0], redm[1]), fmaxf(redm[2], redm[3]));
    float sum = 0.f;
#pragma unroll
    for (int i = 0; i < 4; ++i) {
        v[i].x = __expf(v[i].x - mx); v[i].y = __expf(v[i].y - mx);
        v[i].z = __expf(v[i].z - mx); v[i].w = __expf(v[i].w - mx);
        sum += v[i].x + v[i].y + v[i].z + v[i].w;
    }
#pragma unroll
    for (int m = 32; m >= 1; m >>= 1) sum += __shfl_xor(sum, m, 64);
    if (lane == 0) reds[wv] = sum;
    __syncthreads();
    float inv = 1.0f / (reds[0] + reds[1] + reds[2] + reds[3]);
    unsigned short* pb = Pb + row * KLEN;
#pragma unroll
    for (int i = 0; i < 4; ++i) {
        ushort4v h;
        h[0] = f2bf(v[i].x * inv); h[1] = f2bf(v[i].y * inv);
        h[2] = f2bf(v[i].z * inv); h[3] = f2bf(v[i].w * inv);
        *(ushort4v*)(pb + i * 1024 + t * 4) = h;
    }
}

// ---------- generic C = A * B^T GEMM (both operands K-major bf16), fp32 acc ----------
// BM x BN tile, BK=64, 4 waves (2 wm x 2 wn). QK: BM=BN=128, frozen (107 us / 963 TF
// plateau; r1/r2/r4/r6 all regressed). PV/out: BM=BN=64 -> 1024 blocks = 4 blk/CU (r8).
// WEXP (R10, PV only -- BALANCED): every block stages the full P row-panel over its
//   K-loop, so the fp32 attn write-out is distributed by K-tile ownership:
//   block bx writes only tiles with (kt & 7) == bx  -> 8 of 64 tiles per block,
//   each (by,kt) written by exactly one bx, overhead uniform across all CUs.
//   r9's bx==0-only version put 8x the work on 1/8 of blocks -> PV doubled (160 us,
//   MfmaUtil 8.5). Correctness of the fusion itself is r9-proven (passed, absmax
//   bit-identical). Store completion folds into the next barrier's vmcnt drain.
// SWZ (PV/out): z-chunked bijective remap -> XCD n owns batch n (nblk%8==0).
// EPI: 0 = store fp32; 1 = store bf16; 2 = tanh(x + bias[col]) fp32
// REMAP (QK split-bf16, virtual K=1536): A=[Al|Ah], B=[Bh|Bl], 3 panels.
template <int EPI, bool REMAP, int BM, int BN, bool SWZ, bool WEXP>
__global__ __launch_bounds__(256, 4) void gemm_bt(
    const unsigned short* __restrict__ A,
    const unsigned short* __restrict__ Bm,
    float* __restrict__ Cf, unsigned short* __restrict__ Cb,
    const float* __restrict__ bias,
    int Ktiles, long lda, long ldb, long ldc,
    long a_bs, long b_bs, long c_bs) {
    constexpr int MI = BM / 32;                        // A frags per wave (4 or 2)
    constexpr int NF = BN / 32;                        // B frags per wave (4 or 2)
    __shared__ unsigned short sA[BM * 64];
    __shared__ unsigned short sB[BN * 64];

    int bx, by, bz;
    if constexpr (SWZ) {
        int nx = gridDim.x, ny = gridDim.y;
        int nblk = nx * ny * (int)gridDim.z;
        int id = (int)blockIdx.x + nx * ((int)blockIdx.y + ny * (int)blockIdx.z);
        int wid = (id & 7) * (nblk >> 3) + (id >> 3);
        bx = wid % nx;
        int rem = wid / nx;
        by = rem % ny;
        bz = rem / ny;
    } else {
        bx = blockIdx.x; by = blockIdx.y; bz = blockIdx.z;
    }

    const int tid = threadIdx.x;
    const int lane = tid & 63;
    const int wv = tid >> 6;
    const int wm = wv >> 1, wn = wv & 1;
    const int mlane = lane & 15, quad = lane >> 4;
    const unsigned short* Ab = A + (size_t)bz * a_bs + (size_t)by * BM * lda;
    const unsigned short* Bb = Bm + (size_t)bz * b_bs + (size_t)bx * BN * ldb;
    const int r8 = tid >> 3;
    const int c8 = (tid & 7) << 3;
    const int cg = ((tid & 7) ^ ((tid >> 3) & 7)) << 3;
    unsigned short* la = sA + r8 * 64 + c8;
    unsigned short* lb = sB + r8 * 64 + c8;

    floatx4 acc[MI][NF] = {};

    for (int kt = 0; kt < Ktiles; ++kt) {
        long kv = (long)kt * 64;
        long ka = kv, kb = kv;
        if (REMAP) {
            ka = kv < 512 ? kv + 512 : (kv < 1024 ? kv : kv - 1024);
            kb = kv < 1024 ? kv : kv - 1024;
        }
        if (kt) __syncthreads();                       // protect LDS from overwrite
        const unsigned short* ga = Ab + (size_t)r8 * lda + ka + cg;
        const unsigned short* gb = Bb + (size_t)r8 * ldb + kb + cg;
#pragma unroll
        for (int it = 0; it < BM / 32; ++it)
            gload16(ga + (size_t)(it * 32) * lda, la + it * 2048);
#pragma unroll
        for (int it = 0; it < BN / 32; ++it)
            gload16(gb + (size_t)(it * 32) * ldb, lb + it * 2048);
        __syncthreads();                               // drains vmcnt before barrier
#pragma unroll
        for (int s = 0; s < 2; ++s) {
            const int swz = (((s * 4 + quad) ^ (mlane & 7)) << 3);
            short8 af[MI];
#pragma unroll
            for (int i = 0; i < MI; ++i)
                af[i] = *(const short8*)(sA + (wm * (BM / 2) + i * 16 + mlane) * 64 + swz);
#pragma unroll
            for (int j = 0; j < NF; ++j) {             // stream bf: keeps live regs low
                short8 bfj = *(const short8*)(sB + (wn * (BN / 2) + j * 16 + mlane) * 64 + swz);
#pragma unroll
                for (int i = 0; i < MI; ++i)
                    acc[i][j] = __builtin_amdgcn_mfma_f32_16x16x32_bf16(af[i], bfj, acc[i][j], 0, 0, 0);
            }
        }
        if constexpr (WEXP) {
            if ((kt & 7) == bx) {                      // balanced K-tile ownership
                // expand this block's staged A-tile (bf16 P) -> fp32 attn.
                // Thread (r8, cg) staged chunk cg of rows r8 + it*32; LDS tile is
                // valid until the next iteration's first barrier.
                float* ax = Cf + (size_t)bz * a_bs + (size_t)(by * BM + r8) * lda + kv + cg;
#pragma unroll
                for (int it = 0; it < BM / 32; ++it) {
                    ushort8v pv = *(const ushort8v*)(la + it * 2048);
                    float4 f0, f1;
                    f0.x = bf2f(pv[0]); f0.y = bf2f(pv[1]); f0.z = bf2f(pv[2]); f0.w = bf2f(pv[3]);
                    f1.x = bf2f(pv[4]); f1.y = bf2f(pv[5]); f1.z = bf2f(pv[6]); f1.w = bf2f(pv[7]);
                    *(float4*)(ax + (size_t)(it * 32) * lda) = f0;
                    *(float4*)(ax + (size_t)(it * 32) * lda + 4) = f1;
                }
            }
        }
    }

    // epilogue: C/D layout col=lane&15, row=quad*4+reg
    size_t crow0 = (size_t)by * BM + wm * (BM / 2) + quad * 4;
    size_t ccol0 = (size_t)bx * BN + wn * (BN / 2) + mlane;
    size_t cbase = (size_t)bz * c_bs;
#pragma unroll
    for (int i = 0; i < MI; ++i) {
#pragma unroll
        for (int j = 0; j < NF; ++j) {
            size_t gr = crow0 + i * 16;
            size_t gc = ccol0 + j * 16;
#pragma unroll
            for (int r = 0; r < 4; ++r) {
                float vv = acc[i][j][r];
                size_t off = cbase + (gr + r) * ldc + gc;
                if (EPI == 0) Cf[off] = vv;
                else if (EPI == 1) Cb[off] = f2bf(vv);
                else Cf[off] = fast_tanh(vv + bias[gc]);
            }
        }
    }
}

extern "C" void kernel_launch(void* const* d_in, const int* in_sizes, int n_in,
                              void* d_out, int out_size, void* d_ws, size_t ws_size,
                              hipStream_t stream) {
    (void)in_sizes; (void)n_in; (void)out_size; (void)ws_size;
    const float* outp = (const float*)d_in[0];   // [8,1024,512]
    const float* ctx  = (const float*)d_in[1];   // [8,4096,512]
    const float* W    = (const float*)d_in[2];   // [512,1024]  (already K-major for C=A*W^T)
    const float* bias = (const float*)d_in[3];   // [512]

    float* out0 = (float*)d_out;                              // [8,1024,512]
    float* attn = out0 + (size_t)NB * QLEN * DIMM;            // [8,1024,4096]

    unsigned char* w = (unsigned char*)d_ws;
    // Region plan (113 MiB peak, time-aliased):
    //   R1 (16 MiB): A2 = [outLo|outHi]          -> later: combined [mix | outHi]
    //   R2 (64 MiB): B2 = [ctxHi|ctxLo]          -> later: attn bf16 P
    //   R3 (32 MiB): ctxT hi bf16 [b,512,4096]
    //   R4 ( 1 MiB): W bf16
    unsigned short* R1 = (unsigned short*)(w);
    unsigned short* R2 = (unsigned short*)(w + (16ull << 20));
    unsigned short* R3 = (unsigned short*)(w + (80ull << 20));
    unsigned short* R4 = (unsigned short*)(w + (112ull << 20));

    // 1. prep (output split + W convert fused; ctx read once)
    prep_qw<<<4608, 256, 0, stream>>>(outp, W, R1, R4);
    prep_ctx<<<dim3(8, 64, 8), 256, 0, stream>>>(ctx, R2, R3);       // ctx -> B2 + ctxT

    // 2. QK^T split-bf16 (virtual K=1536) -> raw logits (frozen 2-barrier kernel)
    gemm_bt<0, true, 128, 128, false, false><<<dim3(32, 8, 8), 256, 0, stream>>>(
        R1, R2, attn, nullptr, nullptr,
        24, 1024, 1024, 4096,
        (long)QLEN * 1024, (long)KLEN * 1024, (long)QLEN * KLEN);

    // 3. softmax rows: logits -> bf16 P only (fp32 attn write moved into PV)
    softmax_k<<<8192, 256, 0, stream>>>(attn, R2);

    // 4. PV: mix = P_bf16 * ctxT^T -> combined[:,0:512]; every block also expands
    //    its staged P tiles with (kt&7)==bx -> fp32 attn (balanced WEXP).
    gemm_bt<1, false, 64, 64, true, true><<<dim3(8, 16, 8), 256, 0, stream>>>(
        R2, R3, attn, R1, nullptr,
        64, 4096, 4096, 1024,
        (long)QLEN * KLEN, (long)DIMM * KLEN, (long)QLEN * 1024);

    // 5. out = tanh(combined * W^T + b); grid (8,128) = 1024 blocks = 4 blk/CU
    gemm_bt<2, false, 64, 64, true, false><<<dim3(8, 128, 1), 256, 0, stream>>>(
        R1, R4, out0, nullptr, bias,
        16, 1024, 1024, 512, 0, 0, 0);
}